// Round 14
// baseline (527.285 us; speedup 1.0000x reference)
//
#include <hip/hip_runtime.h>
#include <math.h>

#define D 768
#define DF4 192      // D/4
#define SEQ 128
#define TN 256       // docs per block tile
#define NBK 64       // top-k segments per row
#define TOPK 10
#define KSTEPS 24    // 768 / 32
#define NSEG 8       // rescore segments per row
#define CPS 80       // candidates per rescore segment (640/8)

typedef __attribute__((ext_vector_type(8))) short bh8;    // 8 bf16 = 4 VGPR
typedef __attribute__((ext_vector_type(4))) float f32x4;

#define AS1 __attribute__((address_space(1)))
#define AS3 __attribute__((address_space(3)))

__device__ __forceinline__ unsigned short f2bf(float f) {  // RTNE f32->bf16
  unsigned u = __float_as_uint(f);
  return (unsigned short)((u + 0x7FFF + ((u >> 16) & 1)) >> 16);
}

// ---------------- K1: mean over sequence ----------------
__global__ __launch_bounds__(256) void k_mean(const float* __restrict__ q,
                                              float* __restrict__ qmean) {
  int d = blockIdx.x * 256 + threadIdx.x;
  int b = blockIdx.y;
  if (d >= D) return;
  const float* p = q + (long)b * SEQ * D + d;
  float s = 0.f;
  #pragma unroll 8
  for (int i = 0; i < SEQ; ++i) s += p[(long)i * D];
  qmean[b * D + d] = s * (1.0f / SEQ);
}

// ---------------- K2: projection + bias + L2 normalize ----------------
// Emits bf16 qnorm PRE-SWIZZLED (slot' = slot ^ (row&7)) for k_scores' A-LDS.
__global__ __launch_bounds__(256) void k_proj(const float* __restrict__ qmean,
                                              const float* __restrict__ W,
                                              const float* __restrict__ bias,
                                              float* __restrict__ qnorm,
                                              unsigned short* __restrict__ qbf) {
  __shared__ float4 qm[DF4];
  __shared__ float red[256];
  int b = blockIdx.x, t = threadIdx.x;
  for (int i = t; i < DF4; i += 256) qm[i] = ((const float4*)qmean)[b * DF4 + i];
  __syncthreads();
  float myout[3];
  #pragma unroll
  for (int i = 0; i < 3; ++i) {
    int j = t + i * 256;
    const float4* wr = (const float4*)W + (long)j * DF4;
    float a0 = 0.f, a1 = 0.f, a2 = 0.f, a3 = 0.f;
    for (int kk = 0; kk < DF4; ++kk) {
      float4 w = wr[kk]; float4 qv = qm[kk];
      a0 = fmaf(w.x, qv.x, a0); a1 = fmaf(w.y, qv.y, a1);
      a2 = fmaf(w.z, qv.z, a2); a3 = fmaf(w.w, qv.w, a3);
    }
    myout[i] = (a0 + a1) + (a2 + a3) + bias[j];
  }
  float ss = myout[0]*myout[0] + myout[1]*myout[1] + myout[2]*myout[2];
  red[t] = ss;
  __syncthreads();
  for (int h = 128; h > 0; h >>= 1) {
    if (t < h) red[t] += red[t + h];
    __syncthreads();
  }
  float rn = 1.0f / fmaxf(sqrtf(red[0]), 1e-12f);
  #pragma unroll
  for (int i = 0; i < 3; ++i) {
    int j = t + i * 256;
    float v = myout[i] * rn;
    qnorm[b * D + j] = v;
    int slot = j >> 3;
    qbf[b * D + ((slot ^ (b & 7)) << 3) + (j & 7)] = f2bf(v);
  }
}

// ---------------- K3: cosine scores via MFMA bf16 ----------------
// r12/r13-proven numerics & swizzles. r14 change: 2-deep register pipeline.
// r13's schedule exposed ~700cyc of HBM latency per K-step (loads issued at
// step top, consumed by CVTWRITE after only the ~200cyc MFMA phase; 2
// blocks/CU gives little cross-stream hiding). Two named reg sets rgA/rgB
// (static indexing, rule #20) + x2-unrolled loop: loads for step c+2 issue
// at step c, consumed end of step c+1 (~1.8 iterations of cover >> 900cyc).
__global__ __launch_bounds__(256) __attribute__((amdgpu_waves_per_eu(2)))
void k_scores(const float* __restrict__ docs,
              const unsigned short* __restrict__ qbf,
              float* __restrict__ outS, int N) {
  __shared__ f32x4 smem4[81920 / 16];   // 80 KB: A[0,48K) + B dbuf [48K,80K)
  char* sm = (char*)smem4;
  const int t = threadIdx.x, l = t & 63, w = t >> 6;
  const long tile0 = (long)blockIdx.x * TN;
  const char* docsb = (const char*)docs;

  // --- A DMA: 48 KB linear (qbf already swizzled) ---
  {
    const char* qb = (const char*)qbf;
    #pragma unroll
    for (int i = 0; i < 12; ++i) {
      int off = __builtin_amdgcn_readfirstlane((w * 12 + i) << 10);
      __builtin_amdgcn_global_load_lds((const AS1 void*)(qb + off + l * 16),
                                       (AS3 void*)(sm + off), 16, 0, 0);
    }
  }

  // --- staging addresses ---
  // issue j: lane l -> doc (tile0 + w*64 + j*8 + (l>>3)), k-part (l&7)*16B.
  unsigned gbase[8];
  #pragma unroll
  for (int j = 0; j < 8; ++j) {
    long g = tile0 + w * 64 + j * 8 + (l >> 3);
    if (g >= N) g = N - 1;
    gbase[j] = (unsigned)(g * (D * 4)) + (unsigned)((l & 7) * 16);
  }
  // LDS write addr (relative to B buf base); j-stride 512 (swizzle j-invariant)
  int wa0;
  {
    int dl = w * 64 + (l >> 3);
    int slot = (l & 7) >> 1, h = (l & 7) & 1;
    wa0 = dl * 64 + ((slot ^ ((dl >> 1) & 3)) << 4) + h * 8;
  }

  f32x4 rgA[8], rgB[8];
  float ssqp[8];
  #pragma unroll
  for (int j = 0; j < 8; ++j) ssqp[j] = 0.f;
  f32x4 acc[2][4];
  #pragma unroll
  for (int m = 0; m < 2; ++m)
    #pragma unroll
    for (int n = 0; n < 4; ++n) acc[m][n] = (f32x4){0.f, 0.f, 0.f, 0.f};

#define LOADREG(RG, c) do {                                                  \
    unsigned co_ = (unsigned)((c) * 128);                                    \
    _Pragma("unroll")                                                        \
    for (int j_ = 0; j_ < 8; ++j_)                                           \
      RG[j_] = *(const f32x4*)(docsb + (gbase[j_] + co_));                   \
  } while (0)

#define CVTWRITE(buf, RG) do {                                               \
    char* bb_ = sm + 49152 + (buf) * 16384;                                  \
    _Pragma("unroll")                                                        \
    for (int j_ = 0; j_ < 8; ++j_) {                                         \
      f32x4 v_ = RG[j_];                                                     \
      ssqp[j_] = fmaf(v_.x, v_.x, ssqp[j_]);                                 \
      ssqp[j_] = fmaf(v_.y, v_.y, ssqp[j_]);                                 \
      ssqp[j_] = fmaf(v_.z, v_.z, ssqp[j_]);                                 \
      ssqp[j_] = fmaf(v_.w, v_.w, ssqp[j_]);                                 \
      ushort4 u_;                                                            \
      u_.x = f2bf(v_.x); u_.y = f2bf(v_.y);                                  \
      u_.z = f2bf(v_.z); u_.w = f2bf(v_.w);                                  \
      *(ushort4*)(bb_ + (wa0 + j_ * 512)) = u_;                              \
    }                                                                        \
  } while (0)

#define MFMA_STEP(c, buf) do {                                               \
    const char* bb = sm + 49152 + (buf) * 16384;                             \
    bh8 aF[2];                                                               \
    int sA0 = (c) * 4 + (l >> 4);                                            \
    _Pragma("unroll")                                                        \
    for (int m_ = 0; m_ < 2; ++m_) {                                         \
      int r_ = m_ * 16 + (l & 15);                                           \
      aF[m_] = *(const bh8*)(sm + r_ * 1536 + ((sA0 ^ (r_ & 7)) << 4));      \
    }                                                                        \
    _Pragma("unroll")                                                        \
    for (int n_ = 0; n_ < 4; ++n_) {                                         \
      int dl_ = w * 64 + n_ * 16 + (l & 15);                                 \
      bh8 bF = *(const bh8*)(bb + dl_ * 64 +                                 \
                             ((((l >> 4)) ^ ((dl_ >> 1) & 3)) << 4));        \
      acc[0][n_] = __builtin_amdgcn_mfma_f32_16x16x32_bf16(aF[0], bF,        \
                                                           acc[0][n_],0,0,0);\
      acc[1][n_] = __builtin_amdgcn_mfma_f32_16x16x32_bf16(aF[1], bF,        \
                                                           acc[1][n_],0,0,0);\
    }                                                                        \
  } while (0)

  // prologue: step0 staged via rgA; step1 loads in flight via rgB
  LOADREG(rgA, 0);
  CVTWRITE(0, rgA);
  LOADREG(rgB, 1);
  __syncthreads();          // A + B-buf0 ready

  // steady state, x2 unrolled (static rgA/rgB alternation):
  //  even c: load rgA(c+2) | MFMA buf(c&1) | write rgB -> buf^1
  //  odd  c: load rgB(c+2) | MFMA          | write rgA -> buf^1
  #pragma unroll 1
  for (int c = 0; c < KSTEPS; c += 2) {
    {  // even step c (buf = 0 when c%4==0... buf alternates; c even -> buf (c/1)&1)
      int buf = (c) & 1;      // step c data lives in buf (c&1) by induction
      if (c + 2 < KSTEPS) LOADREG(rgA, c + 2);
      MFMA_STEP(c, buf);
      if (c + 1 < KSTEPS) CVTWRITE(buf ^ 1, rgB);
      __syncthreads();
    }
    {  // odd step c+1
      int c1 = c + 1;
      if (c1 < KSTEPS) {
        int buf = (c1) & 1;
        if (c1 + 2 < KSTEPS) LOADREG(rgB, c1 + 2);
        MFMA_STEP(c1, buf);
        if (c1 + 1 < KSTEPS) CVTWRITE(buf ^ 1, rgA);
        __syncthreads();
      }
    }
  }
#undef LOADREG
#undef CVTWRITE
#undef MFMA_STEP

  // --- doc norms: reduce k-slices across the 8 lanes of each doc group ---
  #pragma unroll
  for (int j = 0; j < 8; ++j) {
    ssqp[j] += __shfl_xor(ssqp[j], 1);
    ssqp[j] += __shfl_xor(ssqp[j], 2);
    ssqp[j] += __shfl_xor(ssqp[j], 4);
  }
  float* sSQ = (float*)(sm + 49152);
  if ((l & 7) == 0) {
    #pragma unroll
    for (int j = 0; j < 8; ++j) sSQ[w * 64 + j * 8 + (l >> 3)] = ssqp[j];
  }
  __syncthreads();

  // --- C write: col=lane&15, row=(lane>>4)*4+reg (m89-verified) ---
  #pragma unroll
  for (int n = 0; n < 4; ++n) {
    int dl = w * 64 + n * 16 + (l & 15);
    long g = tile0 + dl;
    if (g < N) {
      float rn = 1.0f / fmaxf(sqrtf(sSQ[dl]), 1e-12f);
      #pragma unroll
      for (int m = 0; m < 2; ++m) {
        #pragma unroll
        for (int r = 0; r < 4; ++r) {
          int qrow = m * 16 + (l >> 4) * 4 + r;
          outS[(long)qrow * N + g] = acc[m][n][r] * rn;
        }
      }
    }
  }
}

// ---------------- top-k helpers ----------------
__device__ __forceinline__ void insert10(float v, float p, float bs[10], float bi[10]) {
  bool last = (v > bs[9]) || (v == bs[9] && p < bi[9]);
  if (!last) return;
  #pragma unroll
  for (int j = 9; j >= 1; --j) {
    bool bj  = (v > bs[j])   || (v == bs[j]   && p < bi[j]);
    bool bjm = (v > bs[j-1]) || (v == bs[j-1] && p < bi[j-1]);
    float ns = bj ? (bjm ? bs[j-1] : v) : bs[j];
    float ni = bj ? (bjm ? bi[j-1] : p) : bi[j];
    bs[j] = ns; bi[j] = ni;
  }
  bool b0 = (v > bs[0]) || (v == bs[0] && p < bi[0]);
  if (b0) { bs[0] = v; bi[0] = p; }
}

// shared-LDS 256-thread top-10 merge; result in ms/mi[0]
__device__ __forceinline__ void blockmerge10(float bs[10], float bi[10],
                                             float (*ms)[10], float (*mi)[10],
                                             int t) {
  #pragma unroll
  for (int k = 0; k < 10; ++k) { ms[t][k] = bs[k]; mi[t][k] = bi[k]; }
  __syncthreads();
  for (int h = 128; h > 0; h >>= 1) {
    if (t < h) {
      float os[10], oi[10];
      int x = 0, y = 0;
      #pragma unroll
      for (int k = 0; k < 10; ++k) {
        float sx = ms[t][x], sy = ms[t + h][y];
        float ix = mi[t][x], iy = mi[t + h][y];
        bool ta = (sx > sy) || (sx == sy && ix < iy);
        os[k] = ta ? sx : sy; oi[k] = ta ? ix : iy;
        x += ta ? 1 : 0; y += ta ? 0 : 1;
      }
      #pragma unroll
      for (int k = 0; k < 10; ++k) { ms[t][k] = os[k]; mi[t][k] = oi[k]; }
    }
    __syncthreads();
  }
}

// ---------------- K4: per-(row, segment) top-10 on MFMA scores ----------------
__global__ __launch_bounds__(256) void k_topblk(const float* __restrict__ scores,
                                                float2* __restrict__ btop, int N) {
  const int row = blockIdx.y, seg = blockIdx.x, t = threadIdx.x;
  const int per = (N + NBK - 1) / NBK;
  const int s0 = seg * per;
  const int s1 = (s0 + per < N) ? (s0 + per) : N;
  const float* rp = scores + (long)row * N;
  float bs[10], bi[10];
  #pragma unroll
  for (int k = 0; k < 10; ++k) { bs[k] = -INFINITY; bi[k] = 2.0e9f; }
  for (int p = s0 + t; p < s1; p += 256) insert10(rp[p], (float)p, bs, bi);

  __shared__ float ms[256][10];
  __shared__ float mi[256][10];
  blockmerge10(bs, bi, ms, mi, t);
  if (t == 0) {
    #pragma unroll
    for (int k = 0; k < 10; ++k)
      btop[((long)row * NBK + seg) * 10 + k] = make_float2(ms[0][k], mi[0][k]);
  }
}

// ---------------- K5a: exact f32 rescore, parallel over 8 segments/row -------
__global__ __launch_bounds__(256) void k_rescore(const float* __restrict__ docs,
                                                 const float* __restrict__ qn,
                                                 const float2* __restrict__ btop,
                                                 float2* __restrict__ btop2, int N) {
  const int seg = blockIdx.x, row = blockIdx.y, t = threadIdx.x;
  __shared__ float4 qrow[DF4];
  if (t < DF4) qrow[t] = ((const float4*)qn)[row * DF4 + t];
  __syncthreads();
  float bs[10], bi[10];
  #pragma unroll
  for (int k = 0; k < 10; ++k) { bs[k] = -INFINITY; bi[k] = 2.0e9f; }
  if (t < CPS) {
    float2 c = btop[(long)row * (NBK * 10) + seg * CPS + t];
    int doc = (int)c.y;
    const float4* dp = (const float4*)docs + (long)doc * DF4;
    float a0 = 0.f, a1 = 0.f, a2 = 0.f, a3 = 0.f;
    float s0 = 0.f, s1 = 0.f, s2 = 0.f, s3 = 0.f;
    for (int kk = 0; kk < DF4; ++kk) {
      float4 d4 = dp[kk]; float4 q4 = qrow[kk];
      a0 = fmaf(q4.x, d4.x, a0); a1 = fmaf(q4.y, d4.y, a1);
      a2 = fmaf(q4.z, d4.z, a2); a3 = fmaf(q4.w, d4.w, a3);
      s0 = fmaf(d4.x, d4.x, s0); s1 = fmaf(d4.y, d4.y, s1);
      s2 = fmaf(d4.z, d4.z, s2); s3 = fmaf(d4.w, d4.w, s3);
    }
    float nrm = sqrtf((s0 + s1) + (s2 + s3));
    insert10(((a0 + a1) + (a2 + a3)) / fmaxf(nrm, 1e-12f), c.y, bs, bi);
  }
  __shared__ float ms[256][10];
  __shared__ float mi[256][10];
  blockmerge10(bs, bi, ms, mi, t);
  if (t == 0) {
    #pragma unroll
    for (int k = 0; k < 10; ++k)
      btop2[((long)row * NSEG + seg) * 10 + k] = make_float2(ms[0][k], mi[0][k]);
  }
}

// ---------------- K5b: final 80 -> 10 merge per row --------------------------
__global__ __launch_bounds__(256) void k_topfinal(const float2* __restrict__ btop2,
                                                  float* __restrict__ outIdx) {
  const int row = blockIdx.x, t = threadIdx.x;
  const int M = NSEG * 10;   // 80
  float bs[10], bi[10];
  #pragma unroll
  for (int k = 0; k < 10; ++k) { bs[k] = -INFINITY; bi[k] = 2.0e9f; }
  if (t < M) {
    float2 c = btop2[(long)row * M + t];
    insert10(c.x, c.y, bs, bi);
  }
  __shared__ float ms[256][10];
  __shared__ float mi[256][10];
  blockmerge10(bs, bi, ms, mi, t);
  if (t == 0) {
    #pragma unroll
    for (int k = 0; k < 10; ++k) outIdx[row * TOPK + k] = mi[0][k];
  }
}

extern "C" void kernel_launch(void* const* d_in, const int* in_sizes, int n_in,
                              void* d_out, int out_size, void* d_ws, size_t ws_size,
                              hipStream_t stream) {
  const float* q    = (const float*)d_in[0];   // [32,128,768]
  const float* docs = (const float*)d_in[1];   // [N,768]
  const float* W    = (const float*)d_in[2];   // [768,768]
  const float* bias = (const float*)d_in[3];   // [768]
  const int B = in_sizes[0] / (SEQ * D);       // 32
  const int N = in_sizes[1] / D;               // 500000

  float* out    = (float*)d_out;
  float* outIdx = out;                          // [B*10] indices as float
  float* outS   = out + (long)B * TOPK;         // [B][N] scores

  float* qmean = (float*)d_ws;                               // B*D f32
  float* qnorm = qmean + (long)B * D;                        // B*D f32
  unsigned short* qbf = (unsigned short*)(qnorm + (long)B * D); // B*D bf16 swz
  float2* btop  = (float2*)((char*)qbf + (long)B * D * 2);   // B*NBK*10
  float2* btop2 = btop + (long)B * NBK * 10;                 // B*NSEG*10

  dim3 g1(3, B);
  k_mean<<<g1, 256, 0, stream>>>(q, qmean);
  k_proj<<<B, 256, 0, stream>>>(qmean, W, bias, qnorm, qbf);
  int ntiles = (N + TN - 1) / TN;
  k_scores<<<ntiles, 256, 0, stream>>>(docs, qbf, outS, N);
  dim3 g4(NBK, B);
  k_topblk<<<g4, 256, 0, stream>>>(outS, btop, N);
  dim3 g5(NSEG, B);
  k_rescore<<<g5, 256, 0, stream>>>(docs, qnorm, btop, btop2, N);
  k_topfinal<<<B, 256, 0, stream>>>(btop2, outIdx);
}

// Round 15
// 526.253 us; speedup vs baseline: 1.0020x; 1.0020x over previous
//
#include <hip/hip_runtime.h>
#include <math.h>

#define D 768
#define DF4 192      // D/4
#define SEQ 128
#define TN 256       // docs per block tile
#define NBK 64       // top-k segments per row
#define TOPK 10
#define KSTEPS 24    // 768 / 32
#define NSEG 8       // rescore segments per row
#define CPS 80       // candidates per rescore segment (640/8)

typedef __attribute__((ext_vector_type(8))) short bh8;    // 8 bf16 = 4 VGPR
typedef __attribute__((ext_vector_type(4))) float f32x4;

#define AS1 __attribute__((address_space(1)))
#define AS3 __attribute__((address_space(3)))

__device__ __forceinline__ unsigned short f2bf(float f) {  // RTNE f32->bf16
  unsigned u = __float_as_uint(f);
  return (unsigned short)((u + 0x7FFF + ((u >> 16) & 1)) >> 16);
}

// ---------------- K1: mean over sequence ----------------
__global__ __launch_bounds__(256) void k_mean(const float* __restrict__ q,
                                              float* __restrict__ qmean) {
  int d = blockIdx.x * 256 + threadIdx.x;
  int b = blockIdx.y;
  if (d >= D) return;
  const float* p = q + (long)b * SEQ * D + d;
  float s = 0.f;
  #pragma unroll 8
  for (int i = 0; i < SEQ; ++i) s += p[(long)i * D];
  qmean[b * D + d] = s * (1.0f / SEQ);
}

// ---------------- K2: projection + bias + L2 normalize ----------------
// Emits bf16 qnorm PRE-SWIZZLED (slot' = slot ^ (row&7)) for k_scores' A-LDS.
__global__ __launch_bounds__(256) void k_proj(const float* __restrict__ qmean,
                                              const float* __restrict__ W,
                                              const float* __restrict__ bias,
                                              float* __restrict__ qnorm,
                                              unsigned short* __restrict__ qbf) {
  __shared__ float4 qm[DF4];
  __shared__ float red[256];
  int b = blockIdx.x, t = threadIdx.x;
  for (int i = t; i < DF4; i += 256) qm[i] = ((const float4*)qmean)[b * DF4 + i];
  __syncthreads();
  float myout[3];
  #pragma unroll
  for (int i = 0; i < 3; ++i) {
    int j = t + i * 256;
    const float4* wr = (const float4*)W + (long)j * DF4;
    float a0 = 0.f, a1 = 0.f, a2 = 0.f, a3 = 0.f;
    for (int kk = 0; kk < DF4; ++kk) {
      float4 w = wr[kk]; float4 qv = qm[kk];
      a0 = fmaf(w.x, qv.x, a0); a1 = fmaf(w.y, qv.y, a1);
      a2 = fmaf(w.z, qv.z, a2); a3 = fmaf(w.w, qv.w, a3);
    }
    myout[i] = (a0 + a1) + (a2 + a3) + bias[j];
  }
  float ss = myout[0]*myout[0] + myout[1]*myout[1] + myout[2]*myout[2];
  red[t] = ss;
  __syncthreads();
  for (int h = 128; h > 0; h >>= 1) {
    if (t < h) red[t] += red[t + h];
    __syncthreads();
  }
  float rn = 1.0f / fmaxf(sqrtf(red[0]), 1e-12f);
  #pragma unroll
  for (int i = 0; i < 3; ++i) {
    int j = t + i * 256;
    float v = myout[i] * rn;
    qnorm[b * D + j] = v;
    int slot = j >> 3;
    qbf[b * D + ((slot ^ (b & 7)) << 3) + (j & 7)] = f2bf(v);
  }
}

// ---------------- K3: cosine scores via MFMA bf16 ----------------
// r12/r13/r14-proven numerics & swizzles. r15 change: the in-loop barriers
// become lgkmcnt(0)-only + raw s_barrier (T4). __syncthreads() emits
// s_waitcnt vmcnt(0) before s_barrier — which drained the in-flight rg
// loads EVERY STEP, making r14's 2-deep register pipeline a no-op (r13==r14
// == 527us measured). The loop barriers only need to order LDS (ds_write of
// B before ds_read; reads-before-overwrite); rg consumption is guarded by
// compiler-inserted counted vmcnt at the register use. With the drain gone,
// loads for step c+2 stay in flight across two barriers (vmcnt(8) counted),
// doubling MLP and keeping HBM busy through the barrier.
__global__ __launch_bounds__(256) __attribute__((amdgpu_waves_per_eu(2)))
void k_scores(const float* __restrict__ docs,
              const unsigned short* __restrict__ qbf,
              float* __restrict__ outS, int N) {
  __shared__ f32x4 smem4[81920 / 16];   // 80 KB: A[0,48K) + B dbuf [48K,80K)
  char* sm = (char*)smem4;
  const int t = threadIdx.x, l = t & 63, w = t >> 6;
  const long tile0 = (long)blockIdx.x * TN;
  const char* docsb = (const char*)docs;

  // --- A DMA: 48 KB linear (qbf already swizzled) ---
  {
    const char* qb = (const char*)qbf;
    #pragma unroll
    for (int i = 0; i < 12; ++i) {
      int off = __builtin_amdgcn_readfirstlane((w * 12 + i) << 10);
      __builtin_amdgcn_global_load_lds((const AS1 void*)(qb + off + l * 16),
                                       (AS3 void*)(sm + off), 16, 0, 0);
    }
  }

  // --- staging addresses ---
  // issue j: lane l -> doc (tile0 + w*64 + j*8 + (l>>3)), k-part (l&7)*16B.
  unsigned gbase[8];
  #pragma unroll
  for (int j = 0; j < 8; ++j) {
    long g = tile0 + w * 64 + j * 8 + (l >> 3);
    if (g >= N) g = N - 1;
    gbase[j] = (unsigned)(g * (D * 4)) + (unsigned)((l & 7) * 16);
  }
  // LDS write addr (relative to B buf base); j-stride 512 (swizzle j-invariant)
  int wa0;
  {
    int dl = w * 64 + (l >> 3);
    int slot = (l & 7) >> 1, h = (l & 7) & 1;
    wa0 = dl * 64 + ((slot ^ ((dl >> 1) & 3)) << 4) + h * 8;
  }

  f32x4 rgA[8], rgB[8];
  float ssqp[8];
  #pragma unroll
  for (int j = 0; j < 8; ++j) ssqp[j] = 0.f;
  f32x4 acc[2][4];
  #pragma unroll
  for (int m = 0; m < 2; ++m)
    #pragma unroll
    for (int n = 0; n < 4; ++n) acc[m][n] = (f32x4){0.f, 0.f, 0.f, 0.f};

#define LOADREG(RG, c) do {                                                  \
    unsigned co_ = (unsigned)((c) * 128);                                    \
    _Pragma("unroll")                                                        \
    for (int j_ = 0; j_ < 8; ++j_)                                           \
      RG[j_] = *(const f32x4*)(docsb + (gbase[j_] + co_));                   \
  } while (0)

#define CVTWRITE(buf, RG) do {                                               \
    char* bb_ = sm + 49152 + (buf) * 16384;                                  \
    _Pragma("unroll")                                                        \
    for (int j_ = 0; j_ < 8; ++j_) {                                         \
      f32x4 v_ = RG[j_];                                                     \
      ssqp[j_] = fmaf(v_.x, v_.x, ssqp[j_]);                                 \
      ssqp[j_] = fmaf(v_.y, v_.y, ssqp[j_]);                                 \
      ssqp[j_] = fmaf(v_.z, v_.z, ssqp[j_]);                                 \
      ssqp[j_] = fmaf(v_.w, v_.w, ssqp[j_]);                                 \
      ushort4 u_;                                                            \
      u_.x = f2bf(v_.x); u_.y = f2bf(v_.y);                                  \
      u_.z = f2bf(v_.z); u_.w = f2bf(v_.w);                                  \
      *(ushort4*)(bb_ + (wa0 + j_ * 512)) = u_;                              \
    }                                                                        \
  } while (0)

#define MFMA_STEP(c, buf) do {                                               \
    const char* bb = sm + 49152 + (buf) * 16384;                             \
    bh8 aF[2];                                                               \
    int sA0 = (c) * 4 + (l >> 4);                                            \
    _Pragma("unroll")                                                        \
    for (int m_ = 0; m_ < 2; ++m_) {                                         \
      int r_ = m_ * 16 + (l & 15);                                           \
      aF[m_] = *(const bh8*)(sm + r_ * 1536 + ((sA0 ^ (r_ & 7)) << 4));      \
    }                                                                        \
    _Pragma("unroll")                                                        \
    for (int n_ = 0; n_ < 4; ++n_) {                                         \
      int dl_ = w * 64 + n_ * 16 + (l & 15);                                 \
      bh8 bF = *(const bh8*)(bb + dl_ * 64 +                                 \
                             ((((l >> 4)) ^ ((dl_ >> 1) & 3)) << 4));        \
      acc[0][n_] = __builtin_amdgcn_mfma_f32_16x16x32_bf16(aF[0], bF,        \
                                                           acc[0][n_],0,0,0);\
      acc[1][n_] = __builtin_amdgcn_mfma_f32_16x16x32_bf16(aF[1], bF,        \
                                                           acc[1][n_],0,0,0);\
    }                                                                        \
  } while (0)

// LDS-only barrier: order ds_write/ds_read across waves WITHOUT draining
// in-flight VMEM (T4). sched_barrier(0) per rule #18.
#define BARRIER_LGKM() do {                                                  \
    asm volatile("s_waitcnt lgkmcnt(0)" ::: "memory");                       \
    __builtin_amdgcn_s_barrier();                                            \
    __builtin_amdgcn_sched_barrier(0);                                       \
  } while (0)

  // prologue: step0 staged via rgA; step1 loads in flight via rgB
  LOADREG(rgA, 0);
  CVTWRITE(0, rgA);
  LOADREG(rgB, 1);
  __syncthreads();          // full barrier: A DMA (vmcnt) + B-buf0 ready

  // steady state, x2 unrolled (static rgA/rgB alternation):
  //  even c: load rgA(c+2) | MFMA buf(c&1) | write rgB -> buf^1
  //  odd  c: load rgB(c+2) | MFMA          | write rgA -> buf^1
  #pragma unroll 1
  for (int c = 0; c < KSTEPS; c += 2) {
    {  // even step c
      int buf = (c) & 1;
      if (c + 2 < KSTEPS) LOADREG(rgA, c + 2);
      MFMA_STEP(c, buf);
      if (c + 1 < KSTEPS) CVTWRITE(buf ^ 1, rgB);
      BARRIER_LGKM();
    }
    {  // odd step c+1
      int c1 = c + 1;
      if (c1 < KSTEPS) {
        int buf = (c1) & 1;
        if (c1 + 2 < KSTEPS) LOADREG(rgB, c1 + 2);
        MFMA_STEP(c1, buf);
        if (c1 + 1 < KSTEPS) CVTWRITE(buf ^ 1, rgA);
        BARRIER_LGKM();
      }
    }
  }
#undef LOADREG
#undef CVTWRITE
#undef MFMA_STEP
#undef BARRIER_LGKM

  // --- doc norms: reduce k-slices across the 8 lanes of each doc group ---
  #pragma unroll
  for (int j = 0; j < 8; ++j) {
    ssqp[j] += __shfl_xor(ssqp[j], 1);
    ssqp[j] += __shfl_xor(ssqp[j], 2);
    ssqp[j] += __shfl_xor(ssqp[j], 4);
  }
  float* sSQ = (float*)(sm + 49152);
  __syncthreads();          // full barrier before overlaying B region
  if ((l & 7) == 0) {
    #pragma unroll
    for (int j = 0; j < 8; ++j) sSQ[w * 64 + j * 8 + (l >> 3)] = ssqp[j];
  }
  __syncthreads();

  // --- C write: col=lane&15, row=(lane>>4)*4+reg (m89-verified) ---
  #pragma unroll
  for (int n = 0; n < 4; ++n) {
    int dl = w * 64 + n * 16 + (l & 15);
    long g = tile0 + dl;
    if (g < N) {
      float rn = 1.0f / fmaxf(sqrtf(sSQ[dl]), 1e-12f);
      #pragma unroll
      for (int m = 0; m < 2; ++m) {
        #pragma unroll
        for (int r = 0; r < 4; ++r) {
          int qrow = m * 16 + (l >> 4) * 4 + r;
          outS[(long)qrow * N + g] = acc[m][n][r] * rn;
        }
      }
    }
  }
}

// ---------------- top-k helpers ----------------
__device__ __forceinline__ void insert10(float v, float p, float bs[10], float bi[10]) {
  bool last = (v > bs[9]) || (v == bs[9] && p < bi[9]);
  if (!last) return;
  #pragma unroll
  for (int j = 9; j >= 1; --j) {
    bool bj  = (v > bs[j])   || (v == bs[j]   && p < bi[j]);
    bool bjm = (v > bs[j-1]) || (v == bs[j-1] && p < bi[j-1]);
    float ns = bj ? (bjm ? bs[j-1] : v) : bs[j];
    float ni = bj ? (bjm ? bi[j-1] : p) : bi[j];
    bs[j] = ns; bi[j] = ni;
  }
  bool b0 = (v > bs[0]) || (v == bs[0] && p < bi[0]);
  if (b0) { bs[0] = v; bi[0] = p; }
}

// shared-LDS 256-thread top-10 merge; result in ms/mi[0]
__device__ __forceinline__ void blockmerge10(float bs[10], float bi[10],
                                             float (*ms)[10], float (*mi)[10],
                                             int t) {
  #pragma unroll
  for (int k = 0; k < 10; ++k) { ms[t][k] = bs[k]; mi[t][k] = bi[k]; }
  __syncthreads();
  for (int h = 128; h > 0; h >>= 1) {
    if (t < h) {
      float os[10], oi[10];
      int x = 0, y = 0;
      #pragma unroll
      for (int k = 0; k < 10; ++k) {
        float sx = ms[t][x], sy = ms[t + h][y];
        float ix = mi[t][x], iy = mi[t + h][y];
        bool ta = (sx > sy) || (sx == sy && ix < iy);
        os[k] = ta ? sx : sy; oi[k] = ta ? ix : iy;
        x += ta ? 1 : 0; y += ta ? 0 : 1;
      }
      #pragma unroll
      for (int k = 0; k < 10; ++k) { ms[t][k] = os[k]; mi[t][k] = oi[k]; }
    }
    __syncthreads();
  }
}

// ---------------- K4: per-(row, segment) top-10 on MFMA scores ----------------
__global__ __launch_bounds__(256) void k_topblk(const float* __restrict__ scores,
                                                float2* __restrict__ btop, int N) {
  const int row = blockIdx.y, seg = blockIdx.x, t = threadIdx.x;
  const int per = (N + NBK - 1) / NBK;
  const int s0 = seg * per;
  const int s1 = (s0 + per < N) ? (s0 + per) : N;
  const float* rp = scores + (long)row * N;
  float bs[10], bi[10];
  #pragma unroll
  for (int k = 0; k < 10; ++k) { bs[k] = -INFINITY; bi[k] = 2.0e9f; }
  for (int p = s0 + t; p < s1; p += 256) insert10(rp[p], (float)p, bs, bi);

  __shared__ float ms[256][10];
  __shared__ float mi[256][10];
  blockmerge10(bs, bi, ms, mi, t);
  if (t == 0) {
    #pragma unroll
    for (int k = 0; k < 10; ++k)
      btop[((long)row * NBK + seg) * 10 + k] = make_float2(ms[0][k], mi[0][k]);
  }
}

// ---------------- K5a: exact f32 rescore, parallel over 8 segments/row -------
__global__ __launch_bounds__(256) void k_rescore(const float* __restrict__ docs,
                                                 const float* __restrict__ qn,
                                                 const float2* __restrict__ btop,
                                                 float2* __restrict__ btop2, int N) {
  const int seg = blockIdx.x, row = blockIdx.y, t = threadIdx.x;
  __shared__ float4 qrow[DF4];
  if (t < DF4) qrow[t] = ((const float4*)qn)[row * DF4 + t];
  __syncthreads();
  float bs[10], bi[10];
  #pragma unroll
  for (int k = 0; k < 10; ++k) { bs[k] = -INFINITY; bi[k] = 2.0e9f; }
  if (t < CPS) {
    float2 c = btop[(long)row * (NBK * 10) + seg * CPS + t];
    int doc = (int)c.y;
    const float4* dp = (const float4*)docs + (long)doc * DF4;
    float a0 = 0.f, a1 = 0.f, a2 = 0.f, a3 = 0.f;
    float s0 = 0.f, s1 = 0.f, s2 = 0.f, s3 = 0.f;
    for (int kk = 0; kk < DF4; ++kk) {
      float4 d4 = dp[kk]; float4 q4 = qrow[kk];
      a0 = fmaf(q4.x, d4.x, a0); a1 = fmaf(q4.y, d4.y, a1);
      a2 = fmaf(q4.z, d4.z, a2); a3 = fmaf(q4.w, d4.w, a3);
      s0 = fmaf(d4.x, d4.x, s0); s1 = fmaf(d4.y, d4.y, s1);
      s2 = fmaf(d4.z, d4.z, s2); s3 = fmaf(d4.w, d4.w, s3);
    }
    float nrm = sqrtf((s0 + s1) + (s2 + s3));
    insert10(((a0 + a1) + (a2 + a3)) / fmaxf(nrm, 1e-12f), c.y, bs, bi);
  }
  __shared__ float ms[256][10];
  __shared__ float mi[256][10];
  blockmerge10(bs, bi, ms, mi, t);
  if (t == 0) {
    #pragma unroll
    for (int k = 0; k < 10; ++k)
      btop2[((long)row * NSEG + seg) * 10 + k] = make_float2(ms[0][k], mi[0][k]);
  }
}

// ---------------- K5b: final 80 -> 10 merge per row --------------------------
__global__ __launch_bounds__(256) void k_topfinal(const float2* __restrict__ btop2,
                                                  float* __restrict__ outIdx) {
  const int row = blockIdx.x, t = threadIdx.x;
  const int M = NSEG * 10;   // 80
  float bs[10], bi[10];
  #pragma unroll
  for (int k = 0; k < 10; ++k) { bs[k] = -INFINITY; bi[k] = 2.0e9f; }
  if (t < M) {
    float2 c = btop2[(long)row * M + t];
    insert10(c.x, c.y, bs, bi);
  }
  __shared__ float ms[256][10];
  __shared__ float mi[256][10];
  blockmerge10(bs, bi, ms, mi, t);
  if (t == 0) {
    #pragma unroll
    for (int k = 0; k < 10; ++k) outIdx[row * TOPK + k] = mi[0][k];
  }
}

extern "C" void kernel_launch(void* const* d_in, const int* in_sizes, int n_in,
                              void* d_out, int out_size, void* d_ws, size_t ws_size,
                              hipStream_t stream) {
  const float* q    = (const float*)d_in[0];   // [32,128,768]
  const float* docs = (const float*)d_in[1];   // [N,768]
  const float* W    = (const float*)d_in[2];   // [768,768]
  const float* bias = (const float*)d_in[3];   // [768]
  const int B = in_sizes[0] / (SEQ * D);       // 32
  const int N = in_sizes[1] / D;               // 500000

  float* out    = (float*)d_out;
  float* outIdx = out;                          // [B*10] indices as float
  float* outS   = out + (long)B * TOPK;         // [B][N] scores

  float* qmean = (float*)d_ws;                               // B*D f32
  float* qnorm = qmean + (long)B * D;                        // B*D f32
  unsigned short* qbf = (unsigned short*)(qnorm + (long)B * D); // B*D bf16 swz
  float2* btop  = (float2*)((char*)qbf + (long)B * D * 2);   // B*NBK*10
  float2* btop2 = btop + (long)B * NBK * 10;                 // B*NSEG*10

  dim3 g1(3, B);
  k_mean<<<g1, 256, 0, stream>>>(q, qmean);
  k_proj<<<B, 256, 0, stream>>>(qmean, W, bias, qnorm, qbf);
  int ntiles = (N + TN - 1) / TN;
  k_scores<<<ntiles, 256, 0, stream>>>(docs, qbf, outS, N);
  dim3 g4(NBK, B);
  k_topblk<<<g4, 256, 0, stream>>>(outS, btop, N);
  dim3 g5(NSEG, B);
  k_rescore<<<g5, 256, 0, stream>>>(docs, qnorm, btop, btop2, N);
  k_topfinal<<<B, 256, 0, stream>>>(btop2, outIdx);
}